// Round 1
// baseline (299.379 us; speedup 1.0000x reference)
//
#include <hip/hip_runtime.h>

// Problem constants (from reference): B=4096, N_ELEM=2048, N_NODES=1024, E2=4096
#define B_SAMPLES 4096
#define N_ELEM    2048
#define N_NODES   1024
#define E2        4096
#define BLOCK     256

// One block per batch sample. Reads EA/e/q/r rows fully coalesced (float4),
// does the gather/scatter entirely in LDS, emits one partial sum per block.
__global__ __launch_bounds__(BLOCK) void neq_main_kernel(
    const float* __restrict__ EA, const float* __restrict__ e,
    const float* __restrict__ q,  const float* __restrict__ r,
    const float* __restrict__ vecs, const int* __restrict__ node_ids,
    const int* __restrict__ elem_ids, float* __restrict__ partial)
{
    __shared__ float axial[N_ELEM];        // 8 KiB
    __shared__ float res[N_NODES * 2];     // 8 KiB
    __shared__ float red[BLOCK / 64];

    const int b = blockIdx.x;
    const int t = threadIdx.x;

    // --- Phase 1: axial = EA*e into LDS (coalesced float4) ---
    const float4* EA4 = (const float4*)(EA + (size_t)b * N_ELEM);
    const float4* e4  = (const float4*)(e  + (size_t)b * N_ELEM);
    float4* ax4 = (float4*)axial;
#pragma unroll
    for (int i = 0; i < (N_ELEM / 4) / BLOCK; ++i) {  // 2 iters
        int idx = t + i * BLOCK;
        float4 a  = EA4[idx];
        float4 ee = e4[idx];
        ax4[idx] = make_float4(a.x * ee.x, a.y * ee.y, a.z * ee.z, a.w * ee.w);
    }
    // zero residual accumulator
    float4* res4 = (float4*)res;
#pragma unroll
    for (int i = 0; i < (N_NODES * 2 / 4) / BLOCK; ++i) {  // 2 iters
        res4[t + i * BLOCK] = make_float4(0.f, 0.f, 0.f, 0.f);
    }
    __syncthreads();

    // --- Phase 2: scatter contributions (LDS atomics) ---
#pragma unroll
    for (int i = 0; i < E2 / BLOCK; ++i) {  // 16 iters
        int j = t + i * BLOCK;
        int eid = elem_ids[j];
        int nid = node_ids[j];
        float a = axial[eid];
        float2 v = ((const float2*)vecs)[j];
        atomicAdd(&res[nid * 2 + 0], a * v.x);
        atomicAdd(&res[nid * 2 + 1], a * v.y);
    }
    __syncthreads();

    // --- Phase 3: residual = res - q - r, accumulate squares ---
    const float4* q4 = (const float4*)(q + (size_t)b * N_NODES * 2);
    const float4* r4 = (const float4*)(r + (size_t)b * N_NODES * 2);
    float acc = 0.f;
#pragma unroll
    for (int i = 0; i < (N_NODES * 2 / 4) / BLOCK; ++i) {  // 2 iters
        int idx = t + i * BLOCK;
        float4 rv = res4[idx];
        float4 qq = q4[idx];
        float4 rr = r4[idx];
        float x = rv.x - qq.x - rr.x;
        float y = rv.y - qq.y - rr.y;
        float z = rv.z - qq.z - rr.z;
        float w = rv.w - qq.w - rr.w;
        acc += x * x + y * y + z * z + w * w;
    }

    // wave reduce (64 lanes) then cross-wave via LDS
#pragma unroll
    for (int off = 32; off > 0; off >>= 1)
        acc += __shfl_down(acc, off, 64);
    if ((t & 63) == 0) red[t >> 6] = acc;
    __syncthreads();
    if (t == 0) partial[b] = red[0] + red[1] + red[2] + red[3];
}

// Reduce the 4096 per-block partials and apply the mean scale.
__global__ __launch_bounds__(BLOCK) void neq_reduce_kernel(
    const float* __restrict__ partial, float* __restrict__ out)
{
    __shared__ float red[BLOCK / 64];
    const int t = threadIdx.x;
    float acc = 0.f;
    for (int i = t; i < B_SAMPLES; i += BLOCK) acc += partial[i];
#pragma unroll
    for (int off = 32; off > 0; off >>= 1)
        acc += __shfl_down(acc, off, 64);
    if ((t & 63) == 0) red[t >> 6] = acc;
    __syncthreads();
    if (t == 0) {
        const float inv_n = 1.0f / (float)((size_t)B_SAMPLES * N_NODES * 2);
        out[0] = (red[0] + red[1] + red[2] + red[3]) * inv_n;
    }
}

extern "C" void kernel_launch(void* const* d_in, const int* in_sizes, int n_in,
                              void* d_out, int out_size, void* d_ws, size_t ws_size,
                              hipStream_t stream) {
    const float* EA       = (const float*)d_in[0];
    const float* e        = (const float*)d_in[1];
    const float* q        = (const float*)d_in[2];
    const float* r        = (const float*)d_in[3];
    const float* vecs     = (const float*)d_in[4];
    const int*   node_ids = (const int*)d_in[5];
    const int*   elem_ids = (const int*)d_in[6];

    float* partial = (float*)d_ws;  // B_SAMPLES floats = 16 KiB scratch

    neq_main_kernel<<<B_SAMPLES, BLOCK, 0, stream>>>(
        EA, e, q, r, vecs, node_ids, elem_ids, partial);
    neq_reduce_kernel<<<1, BLOCK, 0, stream>>>(partial, (float*)d_out);
}

// Round 2
// 294.264 us; speedup vs baseline: 1.0174x; 1.0174x over previous
//
#include <hip/hip_runtime.h>

// Problem constants (from reference): B=4096, N_ELEM=2048, N_NODES=1024, E2=4096
#define B_SAMPLES 4096
#define N_ELEM    2048
#define N_NODES   1024
#define E2        4096
#define BLOCK     256
#define ITERS     (E2 / BLOCK)   // 16 scatter iterations per thread

// One block per batch sample. ALL global loads hoisted to kernel top so they
// issue back-to-back (ILP hides HBM/L2 latency); scatter/gather in LDS with
// SoA residual (full 32-bank spread for atomics).
__global__ __launch_bounds__(BLOCK, 4) void neq_main_kernel(
    const float* __restrict__ EA, const float* __restrict__ e,
    const float* __restrict__ q,  const float* __restrict__ r,
    const float* __restrict__ vecs, const int* __restrict__ node_ids,
    const int* __restrict__ elem_ids, float* __restrict__ partial)
{
    __shared__ float axial[N_ELEM];     // 8 KiB
    __shared__ float resx[N_NODES];     // 4 KiB
    __shared__ float resy[N_NODES];     // 4 KiB
    __shared__ float red[BLOCK / 64];

    const int b = blockIdx.x;
    const int t = threadIdx.x;

    // ---------- Hoist ALL global loads (independent, issue together) ----------
    int   eids[ITERS];
    int   nids[ITERS];
    float2 vv[ITERS];
#pragma unroll
    for (int i = 0; i < ITERS; ++i) {
        int j = t + i * BLOCK;
        eids[i] = elem_ids[j];
        nids[i] = node_ids[j];
        vv[i]   = ((const float2*)vecs)[j];
    }

    const float4* EA4 = (const float4*)(EA + (size_t)b * N_ELEM);
    const float4* e4  = (const float4*)(e  + (size_t)b * N_ELEM);
    float4 a0 = EA4[t], a1 = EA4[t + BLOCK];
    float4 m0 = e4[t],  m1 = e4[t + BLOCK];

    const float2* q2 = (const float2*)(q + (size_t)b * N_NODES * 2);
    const float2* r2 = (const float2*)(r + (size_t)b * N_NODES * 2);
    float2 qv[4], rv[4];
#pragma unroll
    for (int k = 0; k < 4; ++k) {
        int n = t + k * BLOCK;
        qv[k] = q2[n];
        rv[k] = r2[n];
    }

    // ---------- Phase 1: axial = EA*e into LDS; zero residual ----------
    float4* ax4 = (float4*)axial;
    ax4[t]         = make_float4(a0.x * m0.x, a0.y * m0.y, a0.z * m0.z, a0.w * m0.w);
    ax4[t + BLOCK] = make_float4(a1.x * m1.x, a1.y * m1.y, a1.z * m1.z, a1.w * m1.w);
    ((float4*)resx)[t] = make_float4(0.f, 0.f, 0.f, 0.f);   // 256 f4 = 1024 floats
    ((float4*)resy)[t] = make_float4(0.f, 0.f, 0.f, 0.f);
    __syncthreads();

    // ---------- Phase 2: scatter (pure LDS, 16-way ILP) ----------
    float ax[ITERS];
#pragma unroll
    for (int i = 0; i < ITERS; ++i) ax[i] = axial[eids[i]];   // independent ds_reads
#pragma unroll
    for (int i = 0; i < ITERS; ++i) {
        atomicAdd(&resx[nids[i]], ax[i] * vv[i].x);
        atomicAdd(&resy[nids[i]], ax[i] * vv[i].y);
    }
    __syncthreads();

    // ---------- Phase 3: residual = res - q - r; sum of squares ----------
    float acc = 0.f;
#pragma unroll
    for (int k = 0; k < 4; ++k) {
        int n = t + k * BLOCK;                 // stride-1 across lanes: conflict-free
        float x = resx[n] - qv[k].x - rv[k].x;
        float y = resy[n] - qv[k].y - rv[k].y;
        acc += x * x + y * y;
    }

    // wave reduce (64 lanes) then cross-wave via LDS
#pragma unroll
    for (int off = 32; off > 0; off >>= 1)
        acc += __shfl_down(acc, off, 64);
    if ((t & 63) == 0) red[t >> 6] = acc;
    __syncthreads();
    if (t == 0) partial[b] = red[0] + red[1] + red[2] + red[3];
}

// Reduce the 4096 per-block partials and apply the mean scale.
__global__ __launch_bounds__(1024) void neq_reduce_kernel(
    const float* __restrict__ partial, float* __restrict__ out)
{
    __shared__ float red[1024 / 64];
    const int t = threadIdx.x;
    float acc = 0.f;
#pragma unroll
    for (int i = 0; i < B_SAMPLES / 1024; ++i) acc += partial[t + i * 1024];
#pragma unroll
    for (int off = 32; off > 0; off >>= 1)
        acc += __shfl_down(acc, off, 64);
    if ((t & 63) == 0) red[t >> 6] = acc;
    __syncthreads();
    if (t == 0) {
        float s = 0.f;
#pragma unroll
        for (int w = 0; w < 1024 / 64; ++w) s += red[w];
        const float inv_n = 1.0f / (float)((size_t)B_SAMPLES * N_NODES * 2);
        out[0] = s * inv_n;
    }
}

extern "C" void kernel_launch(void* const* d_in, const int* in_sizes, int n_in,
                              void* d_out, int out_size, void* d_ws, size_t ws_size,
                              hipStream_t stream) {
    const float* EA       = (const float*)d_in[0];
    const float* e        = (const float*)d_in[1];
    const float* q        = (const float*)d_in[2];
    const float* r        = (const float*)d_in[3];
    const float* vecs     = (const float*)d_in[4];
    const int*   node_ids = (const int*)d_in[5];
    const int*   elem_ids = (const int*)d_in[6];

    float* partial = (float*)d_ws;  // B_SAMPLES floats = 16 KiB scratch

    neq_main_kernel<<<B_SAMPLES, BLOCK, 0, stream>>>(
        EA, e, q, r, vecs, node_ids, elem_ids, partial);
    neq_reduce_kernel<<<1, 1024, 0, stream>>>(partial, (float*)d_out);
}

// Round 3
// 192.693 us; speedup vs baseline: 1.5537x; 1.5271x over previous
//
#include <hip/hip_runtime.h>

// Problem constants (from reference): B=4096, N_ELEM=2048, N_NODES=1024, E2=4096
#define B_SAMPLES 4096
#define N_ELEM    2048
#define N_NODES   1024
#define E2        4096
#define BLOCK     256
#define SLOTS     32          // max incidence entries per node (Poisson mean 4; P(>32) ~ 0)
#define NODES_PER_THREAD (N_NODES / BLOCK)   // 4

// Workspace layout (bytes):
//   [0, 4K)          : cnt[N_NODES]            (int)
//   [4K, 4K+512K)    : ell[SLOTS][N_NODES]     (float4 {wx, wy, bitcast(eid), pad})
//   [516K+4K, +16K)  : partial[B_SAMPLES]      (float)
#define WS_CNT_OFF   0
#define WS_ELL_OFF   4096
#define WS_PART_OFF  (4096 + SLOTS * N_NODES * 16)

// ---------------------------------------------------------------------------
// Setup: build zero-padded transposed-ELL from (node_ids, elem_ids, vecs).
// One block; runs every launch (ws is re-poisoned). ~few µs.
// ---------------------------------------------------------------------------
__global__ __launch_bounds__(1024) void neq_setup_kernel(
    const float* __restrict__ vecs, const int* __restrict__ node_ids,
    const int* __restrict__ elem_ids, int* __restrict__ cnt,
    float4* __restrict__ ell)
{
    __shared__ int cnt_s[N_NODES];
    const int t = threadIdx.x;
    cnt_s[t] = 0;
    // zero the whole ELL table (padding entries must be {0,0,eid=0})
    const int total4 = SLOTS * N_NODES;          // 32768 float4s
#pragma unroll
    for (int i = 0; i < total4 / 1024; ++i)
        ell[t + i * 1024] = make_float4(0.f, 0.f, 0.f, 0.f);
    __syncthreads();   // drains vmem: zero-stores complete before scatter writes

#pragma unroll
    for (int i = 0; i < E2 / 1024; ++i) {
        int j = t + i * 1024;
        int nid = node_ids[j];
        int eid = elem_ids[j];
        float2 v = ((const float2*)vecs)[j];
        int slot = atomicAdd(&cnt_s[nid], 1);
        if (slot < SLOTS) {
            float4 pk;
            pk.x = v.x;
            pk.y = v.y;
            pk.z = __int_as_float(eid);
            pk.w = 0.f;
            ell[slot * N_NODES + nid] = pk;
        }
    }
    __syncthreads();
    cnt[t] = min(cnt_s[t], SLOTS);
}

// ---------------------------------------------------------------------------
// Main: one block per sample. axial=EA*e into LDS; per-node GATHER via ELL
// (no atomics anywhere); fused residual + sum-of-squares reduction.
// ---------------------------------------------------------------------------
__global__ __launch_bounds__(BLOCK) void neq_main_kernel(
    const float* __restrict__ EA, const float* __restrict__ e,
    const float* __restrict__ q,  const float* __restrict__ r,
    const int* __restrict__ cnt, const float4* __restrict__ ell,
    float* __restrict__ partial)
{
    __shared__ float axial[N_ELEM];     // 8 KiB
    __shared__ float red[BLOCK / 64];

    const int b = blockIdx.x;
    const int t = threadIdx.x;

    // ---- hoisted global loads ----
    const float4* EA4 = (const float4*)(EA + (size_t)b * N_ELEM);
    const float4* e4  = (const float4*)(e  + (size_t)b * N_ELEM);
    float4 a0 = EA4[t], a1 = EA4[t + BLOCK];
    float4 m0 = e4[t],  m1 = e4[t + BLOCK];

    int c[NODES_PER_THREAD];
    float2 qv[NODES_PER_THREAD], rv[NODES_PER_THREAD];
    const float2* q2 = (const float2*)(q + (size_t)b * N_NODES * 2);
    const float2* r2 = (const float2*)(r + (size_t)b * N_NODES * 2);
#pragma unroll
    for (int i = 0; i < NODES_PER_THREAD; ++i) {
        int n = t + i * BLOCK;
        c[i]  = cnt[n];
        qv[i] = q2[n];
        rv[i] = r2[n];
    }

    // ---- axial = EA*e into LDS ----
    float4* ax4 = (float4*)axial;
    ax4[t]         = make_float4(a0.x * m0.x, a0.y * m0.y, a0.z * m0.z, a0.w * m0.w);
    ax4[t + BLOCK] = make_float4(a1.x * m1.x, a1.y * m1.y, a1.z * m1.z, a1.w * m1.w);
    __syncthreads();

    // ---- per-node gather (branchless body; ELL is zero-padded) ----
    float accx[NODES_PER_THREAD] = {0.f, 0.f, 0.f, 0.f};
    float accy[NODES_PER_THREAD] = {0.f, 0.f, 0.f, 0.f};
    int kmax = max(max(c[0], c[1]), max(c[2], c[3]));
    for (int k = 0; k < kmax; ++k) {
        const float4* row = ell + k * N_NODES + t;
#pragma unroll
        for (int i = 0; i < NODES_PER_THREAD; ++i) {
            float4 pk = row[i * BLOCK];            // coalesced: lanes->consecutive nodes
            int eid  = __float_as_int(pk.z);
            float ax = axial[eid];                 // LDS gather, ~2-way aliasing (free)
            accx[i] += ax * pk.x;
            accy[i] += ax * pk.y;
        }
    }

    // ---- residual and sum of squares ----
    float acc = 0.f;
#pragma unroll
    for (int i = 0; i < NODES_PER_THREAD; ++i) {
        float x = accx[i] - qv[i].x - rv[i].x;
        float y = accy[i] - qv[i].y - rv[i].y;
        acc += x * x + y * y;
    }

    // ---- wave + block reduce ----
#pragma unroll
    for (int off = 32; off > 0; off >>= 1)
        acc += __shfl_down(acc, off, 64);
    if ((t & 63) == 0) red[t >> 6] = acc;
    __syncthreads();
    if (t == 0) partial[b] = red[0] + red[1] + red[2] + red[3];
}

// Reduce the 4096 per-block partials and apply the mean scale.
__global__ __launch_bounds__(1024) void neq_reduce_kernel(
    const float* __restrict__ partial, float* __restrict__ out)
{
    __shared__ float red[1024 / 64];
    const int t = threadIdx.x;
    float acc = 0.f;
#pragma unroll
    for (int i = 0; i < B_SAMPLES / 1024; ++i) acc += partial[t + i * 1024];
#pragma unroll
    for (int off = 32; off > 0; off >>= 1)
        acc += __shfl_down(acc, off, 64);
    if ((t & 63) == 0) red[t >> 6] = acc;
    __syncthreads();
    if (t == 0) {
        float s = 0.f;
#pragma unroll
        for (int w = 0; w < 1024 / 64; ++w) s += red[w];
        const float inv_n = 1.0f / (float)((size_t)B_SAMPLES * N_NODES * 2);
        out[0] = s * inv_n;
    }
}

extern "C" void kernel_launch(void* const* d_in, const int* in_sizes, int n_in,
                              void* d_out, int out_size, void* d_ws, size_t ws_size,
                              hipStream_t stream) {
    const float* EA       = (const float*)d_in[0];
    const float* e        = (const float*)d_in[1];
    const float* q        = (const float*)d_in[2];
    const float* r        = (const float*)d_in[3];
    const float* vecs     = (const float*)d_in[4];
    const int*   node_ids = (const int*)d_in[5];
    const int*   elem_ids = (const int*)d_in[6];

    char* ws = (char*)d_ws;
    int*    cnt     = (int*)(ws + WS_CNT_OFF);
    float4* ell     = (float4*)(ws + WS_ELL_OFF);
    float*  partial = (float*)(ws + WS_PART_OFF);

    neq_setup_kernel<<<1, 1024, 0, stream>>>(vecs, node_ids, elem_ids, cnt, ell);
    neq_main_kernel<<<B_SAMPLES, BLOCK, 0, stream>>>(
        EA, e, q, r, cnt, ell, partial);
    neq_reduce_kernel<<<1, 1024, 0, stream>>>(partial, (float*)d_out);
}

// Round 4
// 162.423 us; speedup vs baseline: 1.8432x; 1.1864x over previous
//
#include <hip/hip_runtime.h>

// Problem constants (from reference): B=4096, N_ELEM=2048, N_NODES=1024, E2=4096
#define B_SAMPLES 4096
#define N_ELEM    2048
#define N_NODES   1024
#define E2        4096
#define BLOCK     256
#define SLOTS     32                     // max entries/node (Poisson mean 4; P(>=32) ~ 1e-15)
#define S         4                      // samples per main block
#define MAIN_BLOCKS (B_SAMPLES / S)      // 1024

// Workspace layout (bytes):
//   [0, 4K)        : cnt[N_NODES]          (int)
//   [4K, 4K+512K)  : ell[SLOTS][N_NODES]   (float4 {wx, wy, bitcast(eid), pad})
//   [4K+512K, ...) : partial[MAIN_BLOCKS]  (float)
#define WS_CNT_OFF   0
#define WS_ELL_OFF   4096
#define WS_PART_OFF  (4096 + SLOTS * N_NODES * 16)

// ---------------------------------------------------------------------------
// Setup A: zero ELL table + counters. 128 blocks x 256 = one float4 each.
// ---------------------------------------------------------------------------
__global__ __launch_bounds__(BLOCK) void neq_zero_kernel(
    float4* __restrict__ ell, int* __restrict__ cnt)
{
    const int i = blockIdx.x * BLOCK + threadIdx.x;      // 0 .. 32767
    ell[i] = make_float4(0.f, 0.f, 0.f, 0.f);
    if (i < N_NODES) cnt[i] = 0;
}

// ---------------------------------------------------------------------------
// Setup B: build transposed-ELL via global atomics (order-independent sum).
// 16 blocks x 256 = one incidence entry each.
// ---------------------------------------------------------------------------
__global__ __launch_bounds__(BLOCK) void neq_build_kernel(
    const float* __restrict__ vecs, const int* __restrict__ node_ids,
    const int* __restrict__ elem_ids, int* __restrict__ cnt,
    float4* __restrict__ ell)
{
    const int j = blockIdx.x * BLOCK + threadIdx.x;      // 0 .. E2-1
    int nid = node_ids[j];
    int eid = elem_ids[j];
    float2 v = ((const float2*)vecs)[j];
    int slot = atomicAdd(&cnt[nid], 1);                  // device-scope
    if (slot < SLOTS) {
        ell[slot * N_NODES + nid] = make_float4(v.x, v.y, __int_as_float(eid), 0.f);
    }
}

// ---------------------------------------------------------------------------
// Main: one block per S samples. axial for S samples sample-interleaved in
// LDS (float4 per elem => one ds_read_b128 per gather); no atomics.
// ---------------------------------------------------------------------------
__global__ __launch_bounds__(BLOCK, 4) void neq_main_kernel(
    const float* __restrict__ EA, const float* __restrict__ e,
    const float* __restrict__ q,  const float* __restrict__ r,
    const int* __restrict__ cnt, const float4* __restrict__ ell,
    float* __restrict__ partial)
{
    __shared__ float4 axial4[N_ELEM];    // 32 KiB: axial4[eid] = {s0,s1,s2,s3}
    __shared__ float red[BLOCK / 64];

    const int b0 = blockIdx.x * S;
    const int t = threadIdx.x;

    // ---- phase 1: axial4[eid] = EA*e for 4 samples (coalesced dword loads,
    //      conflict-free stride-1 ds_write_b128) ----
#pragma unroll
    for (int i = 0; i < N_ELEM / BLOCK; ++i) {           // 8 iters
        int eid = t + i * BLOCK;
        float4 p;
        const float* EAp = EA + (size_t)b0 * N_ELEM + eid;
        const float* ep  = e  + (size_t)b0 * N_ELEM + eid;
        p.x = EAp[0 * N_ELEM] * ep[0 * N_ELEM];
        p.y = EAp[1 * N_ELEM] * ep[1 * N_ELEM];
        p.z = EAp[2 * N_ELEM] * ep[2 * N_ELEM];
        p.w = EAp[3 * N_ELEM] * ep[3 * N_ELEM];
        axial4[eid] = p;
    }

    // per-node counts (thread owns nodes t, t+256, t+512, t+768)
    int c0 = min(cnt[t], SLOTS);
    int c1 = min(cnt[t + 256], SLOTS);
    int c2 = min(cnt[t + 512], SLOTS);
    int c3 = min(cnt[t + 768], SLOTS);
    int kmax = max(max(c0, c1), max(c2, c3));
    __syncthreads();

    // ---- phase 2: gather (zero-padded ELL => branchless body) ----
    float accx[4][S] = {};   // [node i][sample s]
    float accy[4][S] = {};
    for (int k = 0; k < kmax; ++k) {
        const float4* row = ell + k * N_NODES + t;
#pragma unroll
        for (int i = 0; i < 4; ++i) {
            float4 pk = row[i * BLOCK];                  // coalesced 16B
            int eid = __float_as_int(pk.z);
            float4 ax = axial4[eid];                     // one ds_read_b128
            accx[i][0] += ax.x * pk.x;  accy[i][0] += ax.x * pk.y;
            accx[i][1] += ax.y * pk.x;  accy[i][1] += ax.y * pk.y;
            accx[i][2] += ax.z * pk.x;  accy[i][2] += ax.z * pk.y;
            accx[i][3] += ax.w * pk.x;  accy[i][3] += ax.w * pk.y;
        }
    }

    // ---- phase 3: residual & sum of squares (q/r loaded late: low pressure) ----
    float acc = 0.f;
#pragma unroll
    for (int s = 0; s < S; ++s) {
        const float2* q2 = (const float2*)(q + (size_t)(b0 + s) * N_NODES * 2);
        const float2* r2 = (const float2*)(r + (size_t)(b0 + s) * N_NODES * 2);
#pragma unroll
        for (int i = 0; i < 4; ++i) {
            int n = t + i * BLOCK;
            float2 qv = q2[n];
            float2 rv = r2[n];
            float x = accx[i][s] - qv.x - rv.x;
            float y = accy[i][s] - qv.y - rv.y;
            acc += x * x + y * y;
        }
    }

    // ---- wave + block reduce ----
#pragma unroll
    for (int off = 32; off > 0; off >>= 1)
        acc += __shfl_down(acc, off, 64);
    if ((t & 63) == 0) red[t >> 6] = acc;
    __syncthreads();
    if (t == 0) partial[blockIdx.x] = red[0] + red[1] + red[2] + red[3];
}

// Reduce the per-block partials and apply the mean scale.
__global__ __launch_bounds__(1024) void neq_reduce_kernel(
    const float* __restrict__ partial, float* __restrict__ out)
{
    __shared__ float red[1024 / 64];
    const int t = threadIdx.x;
    float acc = partial[t];                              // MAIN_BLOCKS == 1024
#pragma unroll
    for (int off = 32; off > 0; off >>= 1)
        acc += __shfl_down(acc, off, 64);
    if ((t & 63) == 0) red[t >> 6] = acc;
    __syncthreads();
    if (t == 0) {
        float s = 0.f;
#pragma unroll
        for (int w = 0; w < 1024 / 64; ++w) s += red[w];
        const float inv_n = 1.0f / (float)((size_t)B_SAMPLES * N_NODES * 2);
        out[0] = s * inv_n;
    }
}

extern "C" void kernel_launch(void* const* d_in, const int* in_sizes, int n_in,
                              void* d_out, int out_size, void* d_ws, size_t ws_size,
                              hipStream_t stream) {
    const float* EA       = (const float*)d_in[0];
    const float* e        = (const float*)d_in[1];
    const float* q        = (const float*)d_in[2];
    const float* r        = (const float*)d_in[3];
    const float* vecs     = (const float*)d_in[4];
    const int*   node_ids = (const int*)d_in[5];
    const int*   elem_ids = (const int*)d_in[6];

    char* ws = (char*)d_ws;
    int*    cnt     = (int*)(ws + WS_CNT_OFF);
    float4* ell     = (float4*)(ws + WS_ELL_OFF);
    float*  partial = (float*)(ws + WS_PART_OFF);

    neq_zero_kernel<<<(SLOTS * N_NODES) / BLOCK, BLOCK, 0, stream>>>(ell, cnt);
    neq_build_kernel<<<E2 / BLOCK, BLOCK, 0, stream>>>(
        vecs, node_ids, elem_ids, cnt, ell);
    neq_main_kernel<<<MAIN_BLOCKS, BLOCK, 0, stream>>>(
        EA, e, q, r, cnt, ell, partial);
    neq_reduce_kernel<<<1, 1024, 0, stream>>>(partial, (float*)d_out);
}